// Round 12
// baseline (185.037 us; speedup 1.0000x reference)
//
#include <hip/hip_runtime.h>
#include <hip/hip_bf16.h>
#include <hip/hip_fp16.h>
#include <math.h>

#define N_NODES 156
#define NFEAT 256
#define NHID 128
#define BATCH 16384
#define TT 24
#define HLSTM 32
#define G4 128            // 4*HLSTM
#define ALPHA 0.2f
#define XSTRIDE (TT*N_NODES)   // 3744 floats per batch row
#define APAD 172          // LDS A row pitch (shorts): 86 dwords, gcd(86,32)=2 -> ~2-way

typedef __attribute__((ext_vector_type(8))) short bf16x8;
typedef __attribute__((ext_vector_type(4))) float f32x4;

static __device__ __forceinline__ unsigned short f2bf(float f) {
    unsigned u = __float_as_uint(f);
    u += 0x7fffu + ((u >> 16) & 1u);          // RNE
    return (unsigned short)(u >> 16);
}
static __device__ __forceinline__ bf16x8 cv8(float4 a, float4 b) {
    union { __hip_bfloat16 h[8]; bf16x8 v; } u;
    u.h[0] = __float2bfloat16(a.x); u.h[1] = __float2bfloat16(a.y);
    u.h[2] = __float2bfloat16(a.z); u.h[3] = __float2bfloat16(a.w);
    u.h[4] = __float2bfloat16(b.x); u.h[5] = __float2bfloat16(b.y);
    u.h[6] = __float2bfloat16(b.z); u.h[7] = __float2bfloat16(b.w);
    return u.v;
}
static __device__ __forceinline__ float sigm(float x) { return 1.f / (1.f + __expf(-x)); }
static __device__ __forceinline__ float tanh_(float x) { return 1.f - 2.f / (__expf(2.f * x) + 1.f); }

// ---------------- K1: GAT s1/s2 ----
__global__ void k_gat_s(const float* __restrict__ emb,
                        const float* __restrict__ Wr, const float* __restrict__ ar,
                        const float* __restrict__ Wp, const float* __restrict__ ap,
                        float* __restrict__ s_buf /* [2][2][156] */) {
    int i = blockIdx.x;
    int gat = blockIdx.y;
    const float* W = gat ? Wp : Wr;
    const float* a = gat ? ap : ar;
    int j = threadIdx.x; // 0..127
    __shared__ float erow[NFEAT];
    __shared__ float red[128];
    for (int k = j; k < NFEAT; k += 128) erow[k] = emb[i*NFEAT + k];
    __syncthreads();
    float h = 0.f;
    for (int k = 0; k < NFEAT; ++k) h = fmaf(erow[k], W[k*NHID + j], h);
    float v1 = h * a[j];
    float v2 = h * a[NHID + j];
    red[j] = v1; __syncthreads();
    for (int s = 64; s > 0; s >>= 1) { if (j < s) red[j] += red[j+s]; __syncthreads(); }
    if (j == 0) s_buf[(gat*2+0)*N_NODES + i] = red[0];
    __syncthreads();
    red[j] = v2; __syncthreads();
    for (int s = 64; s > 0; s >>= 1) { if (j < s) red[j] += red[j+s]; __syncthreads(); }
    if (j == 0) s_buf[(gat*2+1)*N_NODES + i] = red[0];
}

// ---------------- K2: masked leaky-relu softmax rows -> attn ----------------
__global__ void k_attn(const float* __restrict__ s_buf, const int* __restrict__ adj,
                       float* __restrict__ attn /* [2][156][156] */) {
    int i = blockIdx.x, gat = blockIdx.y;
    int j = threadIdx.x;
    __shared__ float red[256];
    float s1 = s_buf[(gat*2+0)*N_NODES + i];
    bool act = (j < N_NODES);
    float e = -INFINITY;
    if (act) {
        float s2 = s_buf[(gat*2+1)*N_NODES + j];
        float z = s1 + s2;
        z = (z > 0.f) ? z : ALPHA * z;
        if (adj[i*N_NODES + j] <= 0) z = -9e15f;
        e = z;
    }
    red[j] = e; __syncthreads();
    for (int s = 128; s > 0; s >>= 1) { if (j < s) red[j] = fmaxf(red[j], red[j+s]); __syncthreads(); }
    float m = red[0]; __syncthreads();
    float val = act ? __expf(e - m) : 0.f;
    red[j] = val; __syncthreads();
    for (int s = 128; s > 0; s >>= 1) { if (j < s) red[j] += red[j+s]; __syncthreads(); }
    float inv = 1.f / red[0];
    if (act) attn[(gat*N_NODES + i)*N_NODES + j] = val * inv;
}

// ---------------- K3: Mbf = bf16(Wih @ attn) zero-padded to K=160,
//                      Whhbf = bf16(Whh), bias = bih + bhh ------------------
__global__ void k_prep(const float* __restrict__ attn,
                       const float* __restrict__ Wih_r, const float* __restrict__ Wih_p,
                       const float* __restrict__ Whh_r, const float* __restrict__ Whh_p,
                       const float* __restrict__ bih_r, const float* __restrict__ bhh_r,
                       const float* __restrict__ bih_p, const float* __restrict__ bhh_p,
                       unsigned short* __restrict__ Mbf /* [2][128][160] */,
                       unsigned short* __restrict__ Whhbf /* [2][128][32] */,
                       float* __restrict__ bias2 /* [2][128] */) {
    int g = blockIdx.x, gat = blockIdx.y;
    const float* Wih = gat ? Wih_p : Wih_r;
    const float* A = attn + gat*N_NODES*N_NODES;
    int j = threadIdx.x;
    if (j < 160) {
        float acc = 0.f;
        if (j < N_NODES)
            for (int n = 0; n < N_NODES; ++n)
                acc = fmaf(Wih[g*N_NODES + n], A[n*N_NODES + j], acc);
        Mbf[(gat*G4 + g)*160 + j] = f2bf(acc);   // j>=156 -> 0
    }
    if (j < HLSTM)
        Whhbf[(gat*G4 + g)*HLSTM + j] = f2bf((gat ? Whh_p : Whh_r)[g*HLSTM + j]);
    if (g == 0 && j < G4)
        bias2[gat*G4 + j] = gat ? (bih_p[j] + bhh_p[j]) : (bih_r[j] + bhh_r[j]);
}

// ---------------- K4: gates GEMM (pure streaming, no scan) ------------------
// grid (1024, 3), block 256 (4 waves = 2 mhalf x 2 nhalf).
// Block computes gates for 16 batch rows x 8 steps x 128 gate-cols.
// A-tile = x rows (16 contiguous 5KB runs); m index = trel*16 + brow so each
// 16-row MFMA m-tile is ONE step. Output written in MFMA-fragment order:
// gchunk[bg][t][nt][lane][i] fp16 -- the scan consumes the identical layout.
__global__ void __launch_bounds__(256, 2)
k_gemm(const float* __restrict__ x,
       const unsigned short* __restrict__ Mbf,    // [2][128][160] bf16
       unsigned short* __restrict__ gbuf) {       // fp16 frag-ordered chunks
    __shared__ __align__(16) unsigned short As[128*APAD];   // 44 KB

    const int tid = threadIdx.x;
    const int w  = tid >> 6;
    const int l  = tid & 63;
    const int lm = l & 15;
    const int lg = l >> 4;
    const int mhalf = w >> 1, nhalf = w & 1;
    const int bg = blockIdx.x, tg = blockIdx.y;

    // ---- stage A: 16 rows x 8 steps x 156 f32 (contiguous per row-run) ----
    const float* xbase = x + (size_t)bg*16*XSTRIDE + tg*1248;
    #pragma unroll 4
    for (int idx = tid; idx < 4992; idx += 256) {
        int row = idx / 312, rem = idx - row*312;
        float4 v = *(const float4*)(xbase + (size_t)row*XSTRIDE + rem*4);
        int trel = rem / 39, c4 = rem - trel*39;
        union { __hip_bfloat16 h[4]; uint2 u; } cv;
        cv.h[0] = __float2bfloat16(v.x); cv.h[1] = __float2bfloat16(v.y);
        cv.h[2] = __float2bfloat16(v.z); cv.h[3] = __float2bfloat16(v.w);
        *(uint2*)(As + (trel*16 + row)*APAD + c4*4) = cv.u;
    }
    if (tid < 128) *(uint2*)(As + tid*APAD + 156) = make_uint2(0u, 0u);  // K-pad
    __syncthreads();

    // ---- B frags (recent only for tg==0/mhalf==0 steps 0-3) ----
    const unsigned short* Mb = Mbf + ((tg == 0 && mhalf == 0) ? 0 : G4*160);
    bf16x8 bfr[4][5];
    #pragma unroll
    for (int ni = 0; ni < 4; ++ni) {
        int n_ = (nhalf*4 + ni)*16 + lm;
        #pragma unroll
        for (int kf = 0; kf < 5; ++kf)
            bfr[ni][kf] = *(const bf16x8*)(Mb + n_*160 + kf*32 + lg*8);
    }

    f32x4 acc[4][4];
    #pragma unroll
    for (int mi = 0; mi < 4; ++mi)
        #pragma unroll
        for (int ni = 0; ni < 4; ++ni) acc[mi][ni] = (f32x4){0.f, 0.f, 0.f, 0.f};

    #pragma unroll
    for (int kf = 0; kf < 5; ++kf) {
        bf16x8 af[4];
        #pragma unroll
        for (int mi = 0; mi < 4; ++mi)
            af[mi] = *(const bf16x8*)(As + ((mhalf*4 + mi)*16 + lm)*APAD + kf*32 + lg*8);
        #pragma unroll
        for (int mi = 0; mi < 4; ++mi)
            #pragma unroll
            for (int ni = 0; ni < 4; ++ni)
                acc[mi][ni] = __builtin_amdgcn_mfma_f32_16x16x32_bf16(af[mi], bfr[ni][kf], acc[mi][ni], 0, 0, 0);
    }

    // ---- write fragment-ordered fp16 chunks (8B/lane, 512B/wave contiguous) ----
    #pragma unroll
    for (int mi = 0; mi < 4; ++mi) {
        int t = tg*8 + mhalf*4 + mi;
        #pragma unroll
        for (int ni = 0; ni < 4; ++ni) {
            int nt = nhalf*4 + ni;
            union { __half h[4]; uint2 u; } p;
            p.h[0] = __float2half(acc[mi][ni][0]);
            p.h[1] = __float2half(acc[mi][ni][1]);
            p.h[2] = __float2half(acc[mi][ni][2]);
            p.h[3] = __float2half(acc[mi][ni][3]);
            *(uint2*)((char*)gbuf + ((((size_t)bg*24 + t)*8 + nt) << 9) + l*8) = p.u;
        }
    }
}

// ---------------- K5: LSTM scan + fc (wave-local, barrier-free) -------------
// grid 1024, block 64 (ONE wave, 16 batch rows). Gates precomputed in gbuf in
// this wave's exact fragment layout: lane reads its 8B per nt. No B-residency
// pressure (wrec = 32 VGPR), no barriers; double-banked gate prefetch.
__global__ void __launch_bounds__(64, 1)
k_scan(const unsigned short* __restrict__ gbuf,
       const unsigned short* __restrict__ Whhbf,  // [2][128][32] bf16
       const float* __restrict__ bias2,           // [2][128]
       const float* __restrict__ fcW,             // [156][64] f32
       const float* __restrict__ fcb,             // [156]
       float* __restrict__ out) {                 // [16384][156] f32
    __shared__ __align__(16) unsigned short hfr[512];
    __shared__ __align__(16) unsigned short hcat[16*72];

    const int l  = threadIdx.x;
    const int lm = l & 15;
    const int lg = l >> 4;
    const int bg = blockIdx.x;
    const int b0 = bg * 16;
    const char* gb = (const char*)gbuf;

    bf16x8 wrec[8];
    float  bias_v[8];
    float  cst[8];
    unsigned short hrv[8], hpv[8];

#define LOAD_WB(Wb, bs) do {                                                 \
    _Pragma("unroll")                                                        \
    for (int nt = 0; nt < 8; ++nt) {                                         \
        int n_ = nt*16 + lm;                                                 \
        wrec[nt]   = *(const bf16x8*)((Wb) + n_*HLSTM + lg*8);               \
        bias_v[nt] = (bs)[n_];                                               \
    } } while (0)

#define LOADG(R_, T_) do {                                                   \
    _Pragma("unroll")                                                        \
    for (int nt = 0; nt < 8; ++nt)                                           \
        R_[nt] = *(const uint2*)(gb + ((((size_t)bg*24 + (T_))*8 + nt) << 9) + l*8); \
    } while (0)

#define STEP(T_, GC_) do {                                                   \
    bf16x8 hf_ = *(const bf16x8*)(hfr + l*8);                                \
    f32x4 acc[8];                                                            \
    _Pragma("unroll")                                                        \
    for (int nt = 0; nt < 8; ++nt) {                                         \
        const __half2* hp_ = (const __half2*)&GC_[nt];                       \
        float2 f01 = __half22float2(hp_[0]);                                 \
        float2 f23 = __half22float2(hp_[1]);                                 \
        acc[nt] = (f32x4){bias_v[nt] + f01.x, bias_v[nt] + f01.y,            \
                          bias_v[nt] + f23.x, bias_v[nt] + f23.y};           \
    }                                                                        \
    _Pragma("unroll")                                                        \
    for (int nt = 0; nt < 8; ++nt)                                           \
        acc[nt] = __builtin_amdgcn_mfma_f32_16x16x32_bf16(hf_, wrec[nt], acc[nt], 0, 0, 0); \
    _Pragma("unroll")                                                        \
    for (int ds = 0; ds < 2; ++ds)                                           \
        _Pragma("unroll")                                                    \
        for (int i = 0; i < 4; ++i) {                                        \
            int v = ds*4 + i;                                                \
            float si = sigm(acc[0 + ds][i]);                                 \
            float sf = sigm(acc[2 + ds][i]);                                 \
            float tg = tanh_(acc[4 + ds][i]);                                \
            float so = sigm(acc[6 + ds][i]);                                 \
            float c  = sf*cst[v] + si*tg;                                    \
            float h  = so*tanh_(c);                                          \
            int cidx = ((lm>>3) + 2*ds)*128 + (lg*4 + i)*8 + (lm&7);         \
            if ((T_) == 3)           { hrv[v] = f2bf(h); hfr[cidx] = 0; cst[v] = 0.f; } \
            else if ((T_) == TT-1)   { hpv[v] = f2bf(h); }                   \
            else                     { cst[v] = c; hfr[cidx] = f2bf(h); }    \
        }                                                                    \
    if ((T_) == 3) LOAD_WB(Whhbf + G4*HLSTM, bias2 + G4);                    \
    } while (0)

    LOAD_WB(Whhbf, bias2);
    #pragma unroll
    for (int v = 0; v < 8; ++v) cst[v] = 0.f;
    #pragma unroll
    for (int j = 0; j < 8; ++j) hfr[l*8 + j] = 0;

    uint2 gA[8], gB[8];
    LOADG(gA, 0);
    for (int t = 0; t < TT; t += 2) {
        if (t + 1 < TT) LOADG(gB, t + 1);
        STEP(t, gA);
        if (t + 2 < TT) LOADG(gA, t + 2);
        if (t + 1 < TT) STEP(t + 1, gB);
    }

    // ---- fc epilogue: out = [hr|hp] @ fcW^T + fcb (MFMA, K=64) ----
    #pragma unroll
    for (int ds = 0; ds < 2; ++ds)
        #pragma unroll
        for (int i = 0; i < 4; ++i) {
            int r = lg*4 + i, d = lm + 16*ds, v = ds*4 + i;
            hcat[r*72 + d]      = hrv[v];
            hcat[r*72 + 32 + d] = hpv[v];
        }
    __builtin_amdgcn_s_barrier();   // single wave: orders LDS writes vs reads
    {
        bf16x8 ha0 = *(const bf16x8*)(hcat + lm*72 + lg*8);
        bf16x8 ha1 = *(const bf16x8*)(hcat + lm*72 + 32 + lg*8);
        #pragma unroll
        for (int nt = 0; nt < 10; ++nt) {
            int n  = nt*16 + lm;
            int nc = n < 155 ? n : 155;
            const float* wp0 = fcW + nc*64 + lg*8;
            const float* wp1 = fcW + nc*64 + 32 + lg*8;
            bf16x8 wf0 = cv8(*(const float4*)wp0, *(const float4*)(wp0 + 4));
            bf16x8 wf1 = cv8(*(const float4*)wp1, *(const float4*)(wp1 + 4));
            f32x4 fa = (f32x4){0.f, 0.f, 0.f, 0.f};
            fa = __builtin_amdgcn_mfma_f32_16x16x32_bf16(ha0, wf0, fa, 0, 0, 0);
            fa = __builtin_amdgcn_mfma_f32_16x16x32_bf16(ha1, wf1, fa, 0, 0, 0);
            if (n < N_NODES) {
                float bn = fcb[n];
                #pragma unroll
                for (int i = 0; i < 4; ++i)
                    out[(size_t)(b0 + lg*4 + i)*N_NODES + n] = fa[i] + bn;
            }
        }
    }
#undef STEP
#undef LOADG
#undef LOAD_WB
}

extern "C" void kernel_launch(void* const* d_in, const int* in_sizes, int n_in,
                              void* d_out, int out_size, void* d_ws, size_t ws_size,
                              hipStream_t stream) {
    (void)in_sizes; (void)n_in; (void)out_size; (void)ws_size;
    const float* emb   = (const float*)d_in[0];
    const float* x     = (const float*)d_in[1];
    const int*   adj   = (const int*)d_in[2];
    const float* Wr    = (const float*)d_in[3];
    const float* ar    = (const float*)d_in[4];
    const float* Wp    = (const float*)d_in[5];
    const float* ap    = (const float*)d_in[6];
    const float* Wih_r = (const float*)d_in[7];
    const float* Whh_r = (const float*)d_in[8];
    const float* bih_r = (const float*)d_in[9];
    const float* bhh_r = (const float*)d_in[10];
    const float* Wih_p = (const float*)d_in[11];
    const float* Whh_p = (const float*)d_in[12];
    const float* bih_p = (const float*)d_in[13];
    const float* bhh_p = (const float*)d_in[14];
    const float* fcW   = (const float*)d_in[15];
    const float* fcb   = (const float*)d_in[16];
    float* out = (float*)d_out;

    char* ws = (char*)d_ws;
    size_t off = 0;
    auto alloc = [&](size_t bytes) {
        char* p = ws + off;
        off += (bytes + 255) & ~(size_t)255;
        return p;
    };
    float*          attn  = (float*)alloc(2*156*156*sizeof(float));
    float*          sbuf  = (float*)alloc(4*156*sizeof(float));
    unsigned short* Mbf   = (unsigned short*)alloc(2*G4*160*sizeof(unsigned short));
    unsigned short* Whhbf = (unsigned short*)alloc(2*G4*HLSTM*sizeof(unsigned short));
    float*          bias2 = (float*)alloc(2*G4*sizeof(float));
    unsigned short* gbuf  = (unsigned short*)alloc((size_t)BATCH*TT*G4*2);  // 100.7 MB fp16

    k_gat_s<<<dim3(156, 2), 128, 0, stream>>>(emb, Wr, ar, Wp, ap, sbuf);
    k_attn<<<dim3(156, 2), 256, 0, stream>>>(sbuf, adj, attn);
    k_prep<<<dim3(128, 2), 192, 0, stream>>>(attn, Wih_r, Wih_p, Whh_r, Whh_p,
                                             bih_r, bhh_r, bih_p, bhh_p,
                                             Mbf, Whhbf, bias2);
    k_gemm<<<dim3(BATCH/16, TT/8), 256, 0, stream>>>(x, Mbf, gbuf);
    k_scan<<<dim3(BATCH/16), 64, 0, stream>>>(gbuf, Whhbf, bias2, fcW, fcb, out);
}